// Round 3
// baseline (1399.141 us; speedup 1.0000x reference)
//
#include <hip/hip_runtime.h>
#include <hip/hip_bf16.h>

#define LRELU_SLOPE 0.2f

__device__ __forceinline__ float lrelu(float x) { return x > 0.f ? x : LRELU_SLOPE * x; }

// ---------------- utility kernels ----------------
__global__ void k_zero(int* __restrict__ a, int n) {
    int i = blockIdx.x * blockDim.x + threadIdx.x;
    if (i < n) a[i] = 0;
}

__global__ void k_hist(const int* __restrict__ dst, int* __restrict__ deg, int E) {
    int i = blockIdx.x * blockDim.x + threadIdx.x;
    if (i < E) atomicAdd(&deg[dst[i]], 1);
}

// block-level exclusive scan over 1024 elements; writes per-block totals
__global__ __launch_bounds__(1024) void k_scan1(const int* __restrict__ deg, int* __restrict__ off,
                                                int* __restrict__ bsums, int N) {
    int t = threadIdx.x, b = blockIdx.x;
    int idx = b * 1024 + t;
    int v = (idx < N) ? deg[idx] : 0;
    int lane = t & 63, wid = t >> 6;
    int incl = v;
    #pragma unroll
    for (int d = 1; d < 64; d <<= 1) {
        int u = __shfl_up(incl, d);
        if (lane >= d) incl += u;
    }
    __shared__ int ws[16];
    if (lane == 63) ws[wid] = incl;
    __syncthreads();
    if (wid == 0) {
        int wv = (lane < 16) ? ws[lane] : 0;
        #pragma unroll
        for (int d = 1; d < 16; d <<= 1) {
            int u = __shfl_up(wv, d);
            if (lane >= d) wv += u;
        }
        if (lane < 16) ws[lane] = wv;  // inclusive wave sums
    }
    __syncthreads();
    int woff = (wid > 0) ? ws[wid - 1] : 0;
    if (idx < N) off[idx] = woff + incl - v;  // exclusive within block
    if (t == 0) bsums[b] = ws[15];            // block total
}

// single-block exclusive scan of up to 1024 block sums
__global__ __launch_bounds__(1024) void k_scan2(int* __restrict__ bs, int nb) {
    __shared__ int s[1024];
    int t = threadIdx.x;
    s[t] = (t < nb) ? bs[t] : 0;
    __syncthreads();
    for (int d = 1; d < 1024; d <<= 1) {
        int v = (t >= d) ? s[t - d] : 0;
        __syncthreads();
        s[t] += v;
        __syncthreads();
    }
    if (t < nb) bs[t] = t ? s[t - 1] : 0;
}

__global__ __launch_bounds__(1024) void k_scan3(int* __restrict__ off, const int* __restrict__ bs, int N) {
    int i = blockIdx.x * 1024 + threadIdx.x;
    if (i < N) off[i] += bs[blockIdx.x];
}

__global__ void k_scatter(const int* __restrict__ src, const int* __restrict__ dst,
                          const int* __restrict__ off, int* __restrict__ cur,
                          int* __restrict__ csr, int E) {
    int i = blockIdx.x * blockDim.x + threadIdx.x;
    if (i < E) {
        int d = dst[i];
        int pos = off[d] + atomicAdd(&cur[d], 1);
        csr[pos] = src[i];
    }
}

// ---------------- GEMM: XW = X[N,K] @ W[K,64], fused attention logits ----------------
// Block = 64 rows, wave = 16 rows, lane = output column.
// X staged per 64-k chunk via global_load_lds (16B width), double-buffered; each wave
// stages exactly its own 16 rows. Compute reads X as same-address broadcast
// ds_read_b128 (conflict-free), 4 rows interleaved for 4 independent FMA chains.
// W chunk loaded straight from global (lane=col -> coalesced 256B rows, L2-resident).
template <int K>
__global__ __launch_bounds__(256, 4) void k_gemm(const float* __restrict__ X, const float* __restrict__ W,
                                                 const float* __restrict__ a_s, const float* __restrict__ a_d,
                                                 float* __restrict__ XW, float* __restrict__ Ssrc,
                                                 float* __restrict__ Sdst, int N) {
    constexpr int NKC = K / 64;
    constexpr int NBUF = (NKC > 1) ? 2 : 1;
    __shared__ float Xs[NBUF][64 * 64];
    int t = threadIdx.x, lane = t & 63, wid = t >> 6;
    int rbase = blockIdx.x * 64;

    auto stage = [&](int b, int kc) {
        int kbase = kc * 64;
        #pragma unroll
        for (int i = 0; i < 4; i++) {
            int seg = wid * 4 + i;                       // wave-uniform
            int row = rbase + seg * 4 + (lane >> 4);     // 4 rows per instr
            row = row < N ? row : N - 1;
            const float* g = X + (size_t)row * K + kbase + (lane & 15) * 4;
            __builtin_amdgcn_global_load_lds(
                (const __attribute__((address_space(1))) unsigned int*)g,
                (__attribute__((address_space(3))) unsigned int*)&Xs[b][seg * 256],
                16, 0, 0);
        }
    };

    float as = a_s[lane], ad = a_d[lane];
    float acc[16];
    #pragma unroll
    for (int r = 0; r < 16; r++) acc[r] = 0.f;

    stage(0, 0);
    __syncthreads();

    for (int kc = 0; kc < NKC; kc++) {
        if (kc + 1 < NKC) stage((kc + 1) & 1, kc + 1);  // prefetch: in flight during compute

        int kbase = kc * 64;
        float Wreg[64];
        #pragma unroll
        for (int j = 0; j < 64; j++) Wreg[j] = W[(size_t)(kbase + j) * 64 + lane];

        const float* xb = &Xs[kc & (NBUF - 1)][wid * 16 * 64];
        #pragma unroll
        for (int q = 0; q < 4; q++) {
            #pragma unroll
            for (int j4 = 0; j4 < 16; j4++) {
                float4 x0 = *(const float4*)&xb[(q * 4 + 0) * 64 + j4 * 4];
                float4 x1 = *(const float4*)&xb[(q * 4 + 1) * 64 + j4 * 4];
                float4 x2 = *(const float4*)&xb[(q * 4 + 2) * 64 + j4 * 4];
                float4 x3 = *(const float4*)&xb[(q * 4 + 3) * 64 + j4 * 4];
                float w0 = Wreg[j4 * 4], w1 = Wreg[j4 * 4 + 1], w2 = Wreg[j4 * 4 + 2], w3 = Wreg[j4 * 4 + 3];
                acc[q * 4 + 0] += x0.x * w0; acc[q * 4 + 1] += x1.x * w0;
                acc[q * 4 + 2] += x2.x * w0; acc[q * 4 + 3] += x3.x * w0;
                acc[q * 4 + 0] += x0.y * w1; acc[q * 4 + 1] += x1.y * w1;
                acc[q * 4 + 2] += x2.y * w1; acc[q * 4 + 3] += x3.y * w1;
                acc[q * 4 + 0] += x0.z * w2; acc[q * 4 + 1] += x1.z * w2;
                acc[q * 4 + 2] += x2.z * w2; acc[q * 4 + 3] += x3.z * w2;
                acc[q * 4 + 0] += x0.w * w3; acc[q * 4 + 1] += x1.w * w3;
                acc[q * 4 + 2] += x2.w * w3; acc[q * 4 + 3] += x3.w * w3;
            }
        }
        __syncthreads();  // drains prefetch (issued ~2500 cyc ago) + protects buffer reuse
    }

    // epilogue: write XW rows + attention logit reductions
    #pragma unroll
    for (int r = 0; r < 16; r++) {
        int row = rbase + wid * 16 + r;
        if (row < N) {
            XW[(size_t)row * 64 + lane] = acc[r];
            float vs = acc[r] * as, vd = acc[r] * ad;
            #pragma unroll
            for (int d = 32; d > 0; d >>= 1) {
                vs += __shfl_xor(vs, d);
                vd += __shfl_xor(vd, d);
            }
            if (lane == 0) { Ssrc[row] = vs; Sdst[row] = vd; }
        }
    }
}

// ---------------- attention + aggregate: one wave per dst node ----------------
__global__ __launch_bounds__(256) void k_attn(const float* __restrict__ XW, const float* __restrict__ Ssrc,
                                              const float* __restrict__ Sdst, const int* __restrict__ csr,
                                              const int* __restrict__ off, const int* __restrict__ deg,
                                              const float* __restrict__ bias, float* __restrict__ H,
                                              int N, int do_relu) {
    int t = threadIdx.x, lane = t & 63, wid = t >> 6;
    int n = blockIdx.x * 4 + wid;
    if (n >= N) return;
    float sd = Sdst[n];
    int st = off[n], d = deg[n];

    // phase 1: max over edges (lanes parallel over edges); cache first 64 src/e in regs
    float eself = lrelu(Ssrc[n] + sd);
    float m = eself;
    int myS = 0;
    float myE = -1e30f;
    if (lane < d) {
        myS = csr[st + lane];
        myE = lrelu(Ssrc[myS] + sd);
        m = fmaxf(m, myE);
    }
    for (int i = 64 + lane; i < d; i += 64) {
        int s = csr[st + i];
        m = fmaxf(m, lrelu(Ssrc[s] + sd));
    }
    #pragma unroll
    for (int dd = 32; dd > 0; dd >>= 1) m = fmaxf(m, __shfl_xor(m, dd));

    // phase 2: serial over edges, lanes = feature dims
    float w0 = __expf(eself - m);
    float denom = w0;
    float acc = w0 * XW[(size_t)n * 64 + lane];
    int dcap = d < 64 ? d : 64;
    for (int i = 0; i < dcap; i++) {
        int s = __shfl(myS, i);
        float e = __shfl(myE, i);
        float w = __expf(e - m);
        denom += w;
        acc += w * XW[(size_t)s * 64 + lane];
    }
    for (int i = 64; i < d; i++) {
        int s = csr[st + i];
        float e = lrelu(Ssrc[s] + sd);
        float w = __expf(e - m);
        denom += w;
        acc += w * XW[(size_t)s * 64 + lane];
    }
    float o = acc / denom + bias[lane];
    if (do_relu) o = fmaxf(o, 0.f);
    H[(size_t)n * 64 + lane] = o;
}

// ---------------- head: out[i] = [h[u]; h[m]] . fcW + fcb ----------------
__global__ __launch_bounds__(256) void k_head(const float* __restrict__ H, const int* __restrict__ ui,
                                              const int* __restrict__ mi, const float* __restrict__ fcW,
                                              const float* __restrict__ fcb, float* __restrict__ out, int B) {
    int t = threadIdx.x, lane = t & 63, wid = t >> 6;
    int i = blockIdx.x * 4 + wid;
    if (i >= B) return;
    int u = ui[i], m = mi[i];
    float v = H[(size_t)u * 64 + lane] * fcW[lane] + H[(size_t)m * 64 + lane] * fcW[64 + lane];
    #pragma unroll
    for (int dd = 32; dd > 0; dd >>= 1) v += __shfl_xor(v, dd);
    if (lane == 0) out[i] = v + fcb[0];
}

extern "C" void kernel_launch(void* const* d_in, const int* in_sizes, int n_in,
                              void* d_out, int out_size, void* d_ws, size_t ws_size,
                              hipStream_t stream) {
    const float* x   = (const float*)d_in[0];
    const int*   ei  = (const int*)d_in[1];
    const int*   ui  = (const int*)d_in[2];
    const int*   mi  = (const int*)d_in[3];
    const float* W1  = (const float*)d_in[4];
    const float* as1 = (const float*)d_in[5];
    const float* ad1 = (const float*)d_in[6];
    const float* b1  = (const float*)d_in[7];
    const float* W2  = (const float*)d_in[8];
    const float* as2 = (const float*)d_in[9];
    const float* ad2 = (const float*)d_in[10];
    const float* b2  = (const float*)d_in[11];
    const float* fcW = (const float*)d_in[12];
    const float* fcb = (const float*)d_in[13];
    float* out = (float*)d_out;

    const int Hdim = in_sizes[5];            // 64
    const int FIN  = in_sizes[4] / Hdim;     // 256
    const int N    = in_sizes[0] / FIN;      // 100000
    const int E    = in_sizes[1] / 2;        // 1000000
    const int B    = in_sizes[2];            // 16384

    // workspace carve
    char* w = (char*)d_ws;
    auto alloc = [&](size_t bytes) -> void* {
        void* p = (void*)w;
        w += (bytes + 255) & ~(size_t)255;
        return p;
    };
    float* xw   = (float*)alloc((size_t)N * 64 * 4);
    float* hbuf = (float*)alloc((size_t)N * 64 * 4);
    float* ssrc = (float*)alloc((size_t)N * 4);
    float* sdst = (float*)alloc((size_t)N * 4);
    int* degcur = (int*)alloc((size_t)2 * N * 4);  // deg | cur contiguous
    int* deg = degcur;
    int* cur = degcur + N;
    int* offv  = (int*)alloc((size_t)N * 4);
    int* bsums = (int*)alloc((size_t)1024 * 4);
    int* csr   = (int*)alloc((size_t)E * 4);

    const int* esrc = ei;
    const int* edst = ei + E;

    // --- build CSR by dst (shared by both layers) ---
    k_zero<<<(2 * N + 1023) / 1024, 1024, 0, stream>>>(degcur, 2 * N);
    k_hist<<<(E + 255) / 256, 256, 0, stream>>>(edst, deg, E);
    int nb = (N + 1023) / 1024;
    k_scan1<<<nb, 1024, 0, stream>>>(deg, offv, bsums, N);
    k_scan2<<<1, 1024, 0, stream>>>(bsums, nb);
    k_scan3<<<nb, 1024, 0, stream>>>(offv, bsums, N);
    k_scatter<<<(E + 255) / 256, 256, 0, stream>>>(esrc, edst, offv, cur, csr, E);

    const int gemmBlocks = (N + 63) / 64;

    // --- layer 1 ---
    k_gemm<256><<<gemmBlocks, 256, 0, stream>>>(x, W1, as1, ad1, xw, ssrc, sdst, N);
    k_attn<<<(N + 3) / 4, 256, 0, stream>>>(xw, ssrc, sdst, csr, offv, deg, b1, hbuf, N, 1);

    // --- layer 2 (xw buffer reused) ---
    k_gemm<64><<<gemmBlocks, 256, 0, stream>>>(hbuf, W2, as2, ad2, xw, ssrc, sdst, N);
    k_attn<<<(N + 3) / 4, 256, 0, stream>>>(xw, ssrc, sdst, csr, offv, deg, b2, hbuf, N, 0);

    // --- head ---
    k_head<<<(B + 3) / 4, 256, 0, stream>>>(hbuf, ui, mi, fcW, fcb, out, B);
}

// Round 4
// 1019.966 us; speedup vs baseline: 1.3718x; 1.3718x over previous
//
#include <hip/hip_runtime.h>
#include <hip/hip_bf16.h>

#define LRELU_SLOPE 0.2f

__device__ __forceinline__ float lrelu(float x) { return x > 0.f ? x : LRELU_SLOPE * x; }

// ---------------- utility kernels ----------------
__global__ void k_zero(int* __restrict__ a, int n) {
    int i = blockIdx.x * blockDim.x + threadIdx.x;
    if (i < n) a[i] = 0;
}

__global__ void k_hist(const int* __restrict__ dst, int* __restrict__ deg, int E) {
    int i = blockIdx.x * blockDim.x + threadIdx.x;
    if (i < E) atomicAdd(&deg[dst[i]], 1);
}

// block-level exclusive scan over 1024 elements; writes per-block totals
__global__ __launch_bounds__(1024) void k_scan1(const int* __restrict__ deg, int* __restrict__ off,
                                                int* __restrict__ bsums, int N) {
    int t = threadIdx.x, b = blockIdx.x;
    int idx = b * 1024 + t;
    int v = (idx < N) ? deg[idx] : 0;
    int lane = t & 63, wid = t >> 6;
    int incl = v;
    #pragma unroll
    for (int d = 1; d < 64; d <<= 1) {
        int u = __shfl_up(incl, d);
        if (lane >= d) incl += u;
    }
    __shared__ int ws[16];
    if (lane == 63) ws[wid] = incl;
    __syncthreads();
    if (wid == 0) {
        int wv = (lane < 16) ? ws[lane] : 0;
        #pragma unroll
        for (int d = 1; d < 16; d <<= 1) {
            int u = __shfl_up(wv, d);
            if (lane >= d) wv += u;
        }
        if (lane < 16) ws[lane] = wv;  // inclusive wave sums
    }
    __syncthreads();
    int woff = (wid > 0) ? ws[wid - 1] : 0;
    if (idx < N) off[idx] = woff + incl - v;  // exclusive within block
    if (t == 0) bsums[b] = ws[15];            // block total
}

// single-block exclusive scan of up to 1024 block sums
__global__ __launch_bounds__(1024) void k_scan2(int* __restrict__ bs, int nb) {
    __shared__ int s[1024];
    int t = threadIdx.x;
    s[t] = (t < nb) ? bs[t] : 0;
    __syncthreads();
    for (int d = 1; d < 1024; d <<= 1) {
        int v = (t >= d) ? s[t - d] : 0;
        __syncthreads();
        s[t] += v;
        __syncthreads();
    }
    if (t < nb) bs[t] = t ? s[t - 1] : 0;
}

__global__ __launch_bounds__(1024) void k_scan3(int* __restrict__ off, const int* __restrict__ bs, int N) {
    int i = blockIdx.x * 1024 + threadIdx.x;
    if (i < N) off[i] += bs[blockIdx.x];
}

__global__ void k_scatter(const int* __restrict__ src, const int* __restrict__ dst,
                          const int* __restrict__ off, int* __restrict__ cur,
                          int* __restrict__ csr, int E) {
    int i = blockIdx.x * blockDim.x + threadIdx.x;
    if (i < E) {
        int d = dst[i];
        int pos = off[d] + atomicAdd(&cur[d], 1);
        csr[pos] = src[i];
    }
}

// ---------------- GEMM: XW = X[N,K] @ W[K,64], fused attention logits ----------------
// Block = 64 rows, wave = 16 rows, lane = output column.
// X staged per 64-k chunk via global_load_lds (16B width), double-buffered.
// Compute reads X as same-address broadcast ds_read_b128 (conflict-free).
// W loaded from global in 16-wide chunks (lane=col -> coalesced, L1/L2-resident).
// NOTE: plain __launch_bounds__(256) — a min-waves hint here clamped VGPRs to 64
// and spilled Wreg to scratch (round 3: 2.4 GB HBM traffic, 845 us). Keep live
// W regs at 16 to stay well under the allocator's comfort zone.
template <int K>
__global__ __launch_bounds__(256) void k_gemm(const float* __restrict__ X, const float* __restrict__ W,
                                              const float* __restrict__ a_s, const float* __restrict__ a_d,
                                              float* __restrict__ XW, float* __restrict__ Ssrc,
                                              float* __restrict__ Sdst, int N) {
    constexpr int NKC = K / 64;
    constexpr int NBUF = (NKC > 1) ? 2 : 1;
    __shared__ __align__(16) float Xs[NBUF][64 * 64];
    int t = threadIdx.x, lane = t & 63, wid = t >> 6;
    int rbase = blockIdx.x * 64;

    auto stage = [&](int b, int kc) {
        int kbase = kc * 64;
        #pragma unroll
        for (int i = 0; i < 4; i++) {
            int seg = wid * 4 + i;                       // wave-uniform
            int row = rbase + seg * 4 + (lane >> 4);     // 4 rows per instr
            row = row < N ? row : N - 1;
            const float* g = X + (size_t)row * K + kbase + (lane & 15) * 4;
            __builtin_amdgcn_global_load_lds(
                (const __attribute__((address_space(1))) unsigned int*)g,
                (__attribute__((address_space(3))) unsigned int*)&Xs[b][seg * 256],
                16, 0, 0);
        }
    };

    float as = a_s[lane], ad = a_d[lane];
    float acc[16];
    #pragma unroll
    for (int r = 0; r < 16; r++) acc[r] = 0.f;

    stage(0, 0);
    __syncthreads();

    for (int kc = 0; kc < NKC; kc++) {
        if (kc + 1 < NKC) stage((kc + 1) & 1, kc + 1);  // prefetch: in flight during compute

        int kbase = kc * 64;
        const float* xb = &Xs[kc & (NBUF - 1)][wid * 16 * 64];

        #pragma unroll
        for (int jh = 0; jh < 64; jh += 16) {
            float Wreg[16];
            #pragma unroll
            for (int j = 0; j < 16; j++) Wreg[j] = W[(size_t)(kbase + jh + j) * 64 + lane];
            #pragma unroll
            for (int q = 0; q < 4; q++) {
                #pragma unroll
                for (int j4 = 0; j4 < 4; j4++) {
                    float4 x0 = *(const float4*)&xb[(q * 4 + 0) * 64 + jh + j4 * 4];
                    float4 x1 = *(const float4*)&xb[(q * 4 + 1) * 64 + jh + j4 * 4];
                    float4 x2 = *(const float4*)&xb[(q * 4 + 2) * 64 + jh + j4 * 4];
                    float4 x3 = *(const float4*)&xb[(q * 4 + 3) * 64 + jh + j4 * 4];
                    float w0 = Wreg[j4 * 4], w1 = Wreg[j4 * 4 + 1];
                    float w2 = Wreg[j4 * 4 + 2], w3 = Wreg[j4 * 4 + 3];
                    acc[q * 4 + 0] += x0.x * w0; acc[q * 4 + 1] += x1.x * w0;
                    acc[q * 4 + 2] += x2.x * w0; acc[q * 4 + 3] += x3.x * w0;
                    acc[q * 4 + 0] += x0.y * w1; acc[q * 4 + 1] += x1.y * w1;
                    acc[q * 4 + 2] += x2.y * w1; acc[q * 4 + 3] += x3.y * w1;
                    acc[q * 4 + 0] += x0.z * w2; acc[q * 4 + 1] += x1.z * w2;
                    acc[q * 4 + 2] += x2.z * w2; acc[q * 4 + 3] += x3.z * w2;
                    acc[q * 4 + 0] += x0.w * w3; acc[q * 4 + 1] += x1.w * w3;
                    acc[q * 4 + 2] += x2.w * w3; acc[q * 4 + 3] += x3.w * w3;
                }
            }
        }
        __syncthreads();  // drains prefetch (issued ~2500 cyc ago) + protects buffer reuse
    }

    // epilogue: write XW rows + attention logit reductions
    #pragma unroll
    for (int r = 0; r < 16; r++) {
        int row = rbase + wid * 16 + r;
        if (row < N) {
            XW[(size_t)row * 64 + lane] = acc[r];
            float vs = acc[r] * as, vd = acc[r] * ad;
            #pragma unroll
            for (int d = 32; d > 0; d >>= 1) {
                vs += __shfl_xor(vs, d);
                vd += __shfl_xor(vd, d);
            }
            if (lane == 0) { Ssrc[row] = vs; Sdst[row] = vd; }
        }
    }
}

// ---------------- attention + aggregate: one wave per dst node ----------------
__global__ __launch_bounds__(256) void k_attn(const float* __restrict__ XW, const float* __restrict__ Ssrc,
                                              const float* __restrict__ Sdst, const int* __restrict__ csr,
                                              const int* __restrict__ off, const int* __restrict__ deg,
                                              const float* __restrict__ bias, float* __restrict__ H,
                                              int N, int do_relu) {
    int t = threadIdx.x, lane = t & 63, wid = t >> 6;
    int n = blockIdx.x * 4 + wid;
    if (n >= N) return;
    float sd = Sdst[n];
    int st = off[n], d = deg[n];

    // phase 1: max over edges (lanes parallel over edges); cache first 64 src/e in regs
    float eself = lrelu(Ssrc[n] + sd);
    float m = eself;
    int myS = 0;
    float myE = -1e30f;
    if (lane < d) {
        myS = csr[st + lane];
        myE = lrelu(Ssrc[myS] + sd);
        m = fmaxf(m, myE);
    }
    for (int i = 64 + lane; i < d; i += 64) {
        int s = csr[st + i];
        m = fmaxf(m, lrelu(Ssrc[s] + sd));
    }
    #pragma unroll
    for (int dd = 32; dd > 0; dd >>= 1) m = fmaxf(m, __shfl_xor(m, dd));

    // phase 2: serial over edges, lanes = feature dims
    float w0 = __expf(eself - m);
    float denom = w0;
    float acc = w0 * XW[(size_t)n * 64 + lane];
    int dcap = d < 64 ? d : 64;
    for (int i = 0; i < dcap; i++) {
        int s = __shfl(myS, i);
        float e = __shfl(myE, i);
        float w = __expf(e - m);
        denom += w;
        acc += w * XW[(size_t)s * 64 + lane];
    }
    for (int i = 64; i < d; i++) {
        int s = csr[st + i];
        float e = lrelu(Ssrc[s] + sd);
        float w = __expf(e - m);
        denom += w;
        acc += w * XW[(size_t)s * 64 + lane];
    }
    float o = acc / denom + bias[lane];
    if (do_relu) o = fmaxf(o, 0.f);
    H[(size_t)n * 64 + lane] = o;
}

// ---------------- head: out[i] = [h[u]; h[m]] . fcW + fcb ----------------
__global__ __launch_bounds__(256) void k_head(const float* __restrict__ H, const int* __restrict__ ui,
                                              const int* __restrict__ mi, const float* __restrict__ fcW,
                                              const float* __restrict__ fcb, float* __restrict__ out, int B) {
    int t = threadIdx.x, lane = t & 63, wid = t >> 6;
    int i = blockIdx.x * 4 + wid;
    if (i >= B) return;
    int u = ui[i], m = mi[i];
    float v = H[(size_t)u * 64 + lane] * fcW[lane] + H[(size_t)m * 64 + lane] * fcW[64 + lane];
    #pragma unroll
    for (int dd = 32; dd > 0; dd >>= 1) v += __shfl_xor(v, dd);
    if (lane == 0) out[i] = v + fcb[0];
}

extern "C" void kernel_launch(void* const* d_in, const int* in_sizes, int n_in,
                              void* d_out, int out_size, void* d_ws, size_t ws_size,
                              hipStream_t stream) {
    const float* x   = (const float*)d_in[0];
    const int*   ei  = (const int*)d_in[1];
    const int*   ui  = (const int*)d_in[2];
    const int*   mi  = (const int*)d_in[3];
    const float* W1  = (const float*)d_in[4];
    const float* as1 = (const float*)d_in[5];
    const float* ad1 = (const float*)d_in[6];
    const float* b1  = (const float*)d_in[7];
    const float* W2  = (const float*)d_in[8];
    const float* as2 = (const float*)d_in[9];
    const float* ad2 = (const float*)d_in[10];
    const float* b2  = (const float*)d_in[11];
    const float* fcW = (const float*)d_in[12];
    const float* fcb = (const float*)d_in[13];
    float* out = (float*)d_out;

    const int Hdim = in_sizes[5];            // 64
    const int FIN  = in_sizes[4] / Hdim;     // 256
    const int N    = in_sizes[0] / FIN;      // 100000
    const int E    = in_sizes[1] / 2;        // 1000000
    const int B    = in_sizes[2];            // 16384

    // workspace carve
    char* w = (char*)d_ws;
    auto alloc = [&](size_t bytes) -> void* {
        void* p = (void*)w;
        w += (bytes + 255) & ~(size_t)255;
        return p;
    };
    float* xw   = (float*)alloc((size_t)N * 64 * 4);
    float* hbuf = (float*)alloc((size_t)N * 64 * 4);
    float* ssrc = (float*)alloc((size_t)N * 4);
    float* sdst = (float*)alloc((size_t)N * 4);
    int* degcur = (int*)alloc((size_t)2 * N * 4);  // deg | cur contiguous
    int* deg = degcur;
    int* cur = degcur + N;
    int* offv  = (int*)alloc((size_t)N * 4);
    int* bsums = (int*)alloc((size_t)1024 * 4);
    int* csr   = (int*)alloc((size_t)E * 4);

    const int* esrc = ei;
    const int* edst = ei + E;

    // --- build CSR by dst (shared by both layers) ---
    k_zero<<<(2 * N + 1023) / 1024, 1024, 0, stream>>>(degcur, 2 * N);
    k_hist<<<(E + 255) / 256, 256, 0, stream>>>(edst, deg, E);
    int nb = (N + 1023) / 1024;
    k_scan1<<<nb, 1024, 0, stream>>>(deg, offv, bsums, N);
    k_scan2<<<1, 1024, 0, stream>>>(bsums, nb);
    k_scan3<<<nb, 1024, 0, stream>>>(offv, bsums, N);
    k_scatter<<<(E + 255) / 256, 256, 0, stream>>>(esrc, edst, offv, cur, csr, E);

    const int gemmBlocks = (N + 63) / 64;

    // --- layer 1 ---
    k_gemm<256><<<gemmBlocks, 256, 0, stream>>>(x, W1, as1, ad1, xw, ssrc, sdst, N);
    k_attn<<<(N + 3) / 4, 256, 0, stream>>>(xw, ssrc, sdst, csr, offv, deg, b1, hbuf, N, 1);

    // --- layer 2 (xw buffer reused) ---
    k_gemm<64><<<gemmBlocks, 256, 0, stream>>>(hbuf, W2, as2, ad2, xw, ssrc, sdst, N);
    k_attn<<<(N + 3) / 4, 256, 0, stream>>>(xw, ssrc, sdst, csr, offv, deg, b2, hbuf, N, 0);

    // --- head ---
    k_head<<<(B + 3) / 4, 256, 0, stream>>>(hbuf, ui, mi, fcW, fcb, out, B);
}

// Round 5
// 1002.321 us; speedup vs baseline: 1.3959x; 1.0176x over previous
//
#include <hip/hip_runtime.h>
#include <hip/hip_bf16.h>

#define LRELU_SLOPE 0.2f

__device__ __forceinline__ float lrelu(float x) { return x > 0.f ? x : LRELU_SLOPE * x; }

// ---------------- utility kernels ----------------
__global__ void k_zero(int* __restrict__ a, int n) {
    int i = blockIdx.x * blockDim.x + threadIdx.x;
    if (i < n) a[i] = 0;
}

__global__ void k_hist(const int* __restrict__ dst, int* __restrict__ deg, int E) {
    int i = blockIdx.x * blockDim.x + threadIdx.x;
    if (i < E) atomicAdd(&deg[dst[i]], 1);
}

// block-level exclusive scan over 1024 elements; writes per-block totals
__global__ __launch_bounds__(1024) void k_scan1(const int* __restrict__ deg, int* __restrict__ off,
                                                int* __restrict__ bsums, int N) {
    int t = threadIdx.x, b = blockIdx.x;
    int idx = b * 1024 + t;
    int v = (idx < N) ? deg[idx] : 0;
    int lane = t & 63, wid = t >> 6;
    int incl = v;
    #pragma unroll
    for (int d = 1; d < 64; d <<= 1) {
        int u = __shfl_up(incl, d);
        if (lane >= d) incl += u;
    }
    __shared__ int ws[16];
    if (lane == 63) ws[wid] = incl;
    __syncthreads();
    if (wid == 0) {
        int wv = (lane < 16) ? ws[lane] : 0;
        #pragma unroll
        for (int d = 1; d < 16; d <<= 1) {
            int u = __shfl_up(wv, d);
            if (lane >= d) wv += u;
        }
        if (lane < 16) ws[lane] = wv;  // inclusive wave sums
    }
    __syncthreads();
    int woff = (wid > 0) ? ws[wid - 1] : 0;
    if (idx < N) off[idx] = woff + incl - v;  // exclusive within block
    if (t == 0) bsums[b] = ws[15];            // block total
}

// single-block exclusive scan of up to 1024 block sums
__global__ __launch_bounds__(1024) void k_scan2(int* __restrict__ bs, int nb) {
    __shared__ int s[1024];
    int t = threadIdx.x;
    s[t] = (t < nb) ? bs[t] : 0;
    __syncthreads();
    for (int d = 1; d < 1024; d <<= 1) {
        int v = (t >= d) ? s[t - d] : 0;
        __syncthreads();
        s[t] += v;
        __syncthreads();
    }
    if (t < nb) bs[t] = t ? s[t - 1] : 0;
}

__global__ __launch_bounds__(1024) void k_scan3(int* __restrict__ off, const int* __restrict__ bs, int N) {
    int i = blockIdx.x * 1024 + threadIdx.x;
    if (i < N) off[i] += bs[blockIdx.x];
}

__global__ void k_scatter(const int* __restrict__ src, const int* __restrict__ dst,
                          const int* __restrict__ off, int* __restrict__ cur,
                          int* __restrict__ csr, int E) {
    int i = blockIdx.x * blockDim.x + threadIdx.x;
    if (i < E) {
        int d = dst[i];
        int pos = off[d] + atomicAdd(&cur[d], 1);
        csr[pos] = src[i];
    }
}

// ---------------- GEMM: XW = X[N,K] @ W[K,64], fused attention logits ----------------
// Block = 64 rows, wave = 16 rows, lane = output column.
// X staged per 64-k chunk via global_load_lds (16B width), double-buffered.
// Compute reads X as same-address broadcast ds_read_b128 (conflict-free).
// W loaded from global in 16-wide chunks (lane=col -> coalesced, L1/L2-resident).
// REGISTER-PRESSURE HISTORY (do not regress):
//   r3: __launch_bounds__(256,4) clamped VGPR=64 -> Wreg spilled -> 2.4 GB scratch.
//   r4: unclamped -> scheduler hoisted ALL 64 ds_read_b128 + 64 W loads per kc
//       across the full unroll -> VGPR=256 + acc spilled -> 1.45 GB scratch.
//   r5: sched_barrier(0) after each row-quad caps the hoist window (~16 live
//       float4) -> target ~120 VGPR, no spill.
template <int K>
__global__ __launch_bounds__(256) void k_gemm(const float* __restrict__ X, const float* __restrict__ W,
                                              const float* __restrict__ a_s, const float* __restrict__ a_d,
                                              float* __restrict__ XW, float* __restrict__ Ssrc,
                                              float* __restrict__ Sdst, int N) {
    constexpr int NKC = K / 64;
    constexpr int NBUF = (NKC > 1) ? 2 : 1;
    __shared__ __align__(16) float Xs[NBUF][64 * 64];
    int t = threadIdx.x, lane = t & 63, wid = t >> 6;
    int rbase = blockIdx.x * 64;

    auto stage = [&](int b, int kc) {
        int kbase = kc * 64;
        #pragma unroll
        for (int i = 0; i < 4; i++) {
            int seg = wid * 4 + i;                       // wave-uniform
            int row = rbase + seg * 4 + (lane >> 4);     // 4 rows per instr
            row = row < N ? row : N - 1;
            const float* g = X + (size_t)row * K + kbase + (lane & 15) * 4;
            __builtin_amdgcn_global_load_lds(
                (const __attribute__((address_space(1))) unsigned int*)g,
                (__attribute__((address_space(3))) unsigned int*)&Xs[b][seg * 256],
                16, 0, 0);
        }
    };

    float as = a_s[lane], ad = a_d[lane];
    float acc[16];
    #pragma unroll
    for (int r = 0; r < 16; r++) acc[r] = 0.f;

    stage(0, 0);
    __syncthreads();

    for (int kc = 0; kc < NKC; kc++) {
        if (kc + 1 < NKC) stage((kc + 1) & 1, kc + 1);  // prefetch: in flight during compute

        int kbase = kc * 64;
        const float* xb = &Xs[kc & (NBUF - 1)][wid * 16 * 64];

        #pragma unroll
        for (int jh = 0; jh < 64; jh += 16) {
            float Wreg[16];
            #pragma unroll
            for (int j = 0; j < 16; j++) Wreg[j] = W[(size_t)(kbase + jh + j) * 64 + lane];
            #pragma unroll
            for (int q = 0; q < 4; q++) {
                #pragma unroll
                for (int j4 = 0; j4 < 4; j4++) {
                    float4 x0 = *(const float4*)&xb[(q * 4 + 0) * 64 + jh + j4 * 4];
                    float4 x1 = *(const float4*)&xb[(q * 4 + 1) * 64 + jh + j4 * 4];
                    float4 x2 = *(const float4*)&xb[(q * 4 + 2) * 64 + jh + j4 * 4];
                    float4 x3 = *(const float4*)&xb[(q * 4 + 3) * 64 + jh + j4 * 4];
                    float w0 = Wreg[j4 * 4], w1 = Wreg[j4 * 4 + 1];
                    float w2 = Wreg[j4 * 4 + 2], w3 = Wreg[j4 * 4 + 3];
                    acc[q * 4 + 0] += x0.x * w0; acc[q * 4 + 1] += x1.x * w0;
                    acc[q * 4 + 2] += x2.x * w0; acc[q * 4 + 3] += x3.x * w0;
                    acc[q * 4 + 0] += x0.y * w1; acc[q * 4 + 1] += x1.y * w1;
                    acc[q * 4 + 2] += x2.y * w1; acc[q * 4 + 3] += x3.y * w1;
                    acc[q * 4 + 0] += x0.z * w2; acc[q * 4 + 1] += x1.z * w2;
                    acc[q * 4 + 2] += x2.z * w2; acc[q * 4 + 3] += x3.z * w2;
                    acc[q * 4 + 0] += x0.w * w3; acc[q * 4 + 1] += x1.w * w3;
                    acc[q * 4 + 2] += x2.w * w3; acc[q * 4 + 3] += x3.w * w3;
                }
                // cap the scheduler's load-hoist window at one row-quad:
                // without this the compiler batches 64 ds_read_b128 + 64 W loads
                // per kc and spills acc (r4: VGPR=256, 1.45 GB scratch traffic).
                __builtin_amdgcn_sched_barrier(0);
            }
        }
        __syncthreads();  // drains prefetch (issued ~2500 cyc ago) + protects buffer reuse
    }

    // epilogue: write XW rows + attention logit reductions
    #pragma unroll
    for (int r = 0; r < 16; r++) {
        int row = rbase + wid * 16 + r;
        if (row < N) {
            XW[(size_t)row * 64 + lane] = acc[r];
            float vs = acc[r] * as, vd = acc[r] * ad;
            #pragma unroll
            for (int d = 32; d > 0; d >>= 1) {
                vs += __shfl_xor(vs, d);
                vd += __shfl_xor(vd, d);
            }
            if (lane == 0) { Ssrc[row] = vs; Sdst[row] = vd; }
        }
    }
}

// ---------------- attention + aggregate: one wave per dst node ----------------
__global__ __launch_bounds__(256) void k_attn(const float* __restrict__ XW, const float* __restrict__ Ssrc,
                                              const float* __restrict__ Sdst, const int* __restrict__ csr,
                                              const int* __restrict__ off, const int* __restrict__ deg,
                                              const float* __restrict__ bias, float* __restrict__ H,
                                              int N, int do_relu) {
    int t = threadIdx.x, lane = t & 63, wid = t >> 6;
    int n = blockIdx.x * 4 + wid;
    if (n >= N) return;
    float sd = Sdst[n];
    int st = off[n], d = deg[n];

    // phase 1: max over edges (lanes parallel over edges); cache first 64 src/e in regs
    float eself = lrelu(Ssrc[n] + sd);
    float m = eself;
    int myS = 0;
    float myE = -1e30f;
    if (lane < d) {
        myS = csr[st + lane];
        myE = lrelu(Ssrc[myS] + sd);
        m = fmaxf(m, myE);
    }
    for (int i = 64 + lane; i < d; i += 64) {
        int s = csr[st + i];
        m = fmaxf(m, lrelu(Ssrc[s] + sd));
    }
    #pragma unroll
    for (int dd = 32; dd > 0; dd >>= 1) m = fmaxf(m, __shfl_xor(m, dd));

    // phase 2: serial over edges, lanes = feature dims
    float w0 = __expf(eself - m);
    float denom = w0;
    float acc = w0 * XW[(size_t)n * 64 + lane];
    int dcap = d < 64 ? d : 64;
    for (int i = 0; i < dcap; i++) {
        int s = __shfl(myS, i);
        float e = __shfl(myE, i);
        float w = __expf(e - m);
        denom += w;
        acc += w * XW[(size_t)s * 64 + lane];
    }
    for (int i = 64; i < d; i++) {
        int s = csr[st + i];
        float e = lrelu(Ssrc[s] + sd);
        float w = __expf(e - m);
        denom += w;
        acc += w * XW[(size_t)s * 64 + lane];
    }
    float o = acc / denom + bias[lane];
    if (do_relu) o = fmaxf(o, 0.f);
    H[(size_t)n * 64 + lane] = o;
}

// ---------------- head: out[i] = [h[u]; h[m]] . fcW + fcb ----------------
__global__ __launch_bounds__(256) void k_head(const float* __restrict__ H, const int* __restrict__ ui,
                                              const int* __restrict__ mi, const float* __restrict__ fcW,
                                              const float* __restrict__ fcb, float* __restrict__ out, int B) {
    int t = threadIdx.x, lane = t & 63, wid = t >> 6;
    int i = blockIdx.x * 4 + wid;
    if (i >= B) return;
    int u = ui[i], m = mi[i];
    float v = H[(size_t)u * 64 + lane] * fcW[lane] + H[(size_t)m * 64 + lane] * fcW[64 + lane];
    #pragma unroll
    for (int dd = 32; dd > 0; dd >>= 1) v += __shfl_xor(v, dd);
    if (lane == 0) out[i] = v + fcb[0];
}

extern "C" void kernel_launch(void* const* d_in, const int* in_sizes, int n_in,
                              void* d_out, int out_size, void* d_ws, size_t ws_size,
                              hipStream_t stream) {
    const float* x   = (const float*)d_in[0];
    const int*   ei  = (const int*)d_in[1];
    const int*   ui  = (const int*)d_in[2];
    const int*   mi  = (const int*)d_in[3];
    const float* W1  = (const float*)d_in[4];
    const float* as1 = (const float*)d_in[5];
    const float* ad1 = (const float*)d_in[6];
    const float* b1  = (const float*)d_in[7];
    const float* W2  = (const float*)d_in[8];
    const float* as2 = (const float*)d_in[9];
    const float* ad2 = (const float*)d_in[10];
    const float* b2  = (const float*)d_in[11];
    const float* fcW = (const float*)d_in[12];
    const float* fcb = (const float*)d_in[13];
    float* out = (float*)d_out;

    const int Hdim = in_sizes[5];            // 64
    const int FIN  = in_sizes[4] / Hdim;     // 256
    const int N    = in_sizes[0] / FIN;      // 100000
    const int E    = in_sizes[1] / 2;        // 1000000
    const int B    = in_sizes[2];            // 16384

    // workspace carve
    char* w = (char*)d_ws;
    auto alloc = [&](size_t bytes) -> void* {
        void* p = (void*)w;
        w += (bytes + 255) & ~(size_t)255;
        return p;
    };
    float* xw   = (float*)alloc((size_t)N * 64 * 4);
    float* hbuf = (float*)alloc((size_t)N * 64 * 4);
    float* ssrc = (float*)alloc((size_t)N * 4);
    float* sdst = (float*)alloc((size_t)N * 4);
    int* degcur = (int*)alloc((size_t)2 * N * 4);  // deg | cur contiguous
    int* deg = degcur;
    int* cur = degcur + N;
    int* offv  = (int*)alloc((size_t)N * 4);
    int* bsums = (int*)alloc((size_t)1024 * 4);
    int* csr   = (int*)alloc((size_t)E * 4);

    const int* esrc = ei;
    const int* edst = ei + E;

    // --- build CSR by dst (shared by both layers) ---
    k_zero<<<(2 * N + 1023) / 1024, 1024, 0, stream>>>(degcur, 2 * N);
    k_hist<<<(E + 255) / 256, 256, 0, stream>>>(edst, deg, E);
    int nb = (N + 1023) / 1024;
    k_scan1<<<nb, 1024, 0, stream>>>(deg, offv, bsums, N);
    k_scan2<<<1, 1024, 0, stream>>>(bsums, nb);
    k_scan3<<<nb, 1024, 0, stream>>>(offv, bsums, N);
    k_scatter<<<(E + 255) / 256, 256, 0, stream>>>(esrc, edst, offv, cur, csr, E);

    const int gemmBlocks = (N + 63) / 64;

    // --- layer 1 ---
    k_gemm<256><<<gemmBlocks, 256, 0, stream>>>(x, W1, as1, ad1, xw, ssrc, sdst, N);
    k_attn<<<(N + 3) / 4, 256, 0, stream>>>(xw, ssrc, sdst, csr, offv, deg, b1, hbuf, N, 1);

    // --- layer 2 (xw buffer reused) ---
    k_gemm<64><<<gemmBlocks, 256, 0, stream>>>(hbuf, W2, as2, ad2, xw, ssrc, sdst, N);
    k_attn<<<(N + 3) / 4, 256, 0, stream>>>(xw, ssrc, sdst, csr, offv, deg, b2, hbuf, N, 0);

    // --- head ---
    k_head<<<(B + 3) / 4, 256, 0, stream>>>(hbuf, ui, mi, fcW, fcb, out, B);
}

// Round 6
// 558.805 us; speedup vs baseline: 2.5038x; 1.7937x over previous
//
#include <hip/hip_runtime.h>
#include <hip/hip_bf16.h>

#define LRELU_SLOPE 0.2f

__device__ __forceinline__ float lrelu(float x) { return x > 0.f ? x : LRELU_SLOPE * x; }

// ---------------- utility kernels ----------------
__global__ void k_zero(int* __restrict__ a, int n) {
    int i = blockIdx.x * blockDim.x + threadIdx.x;
    if (i < n) a[i] = 0;
}

__global__ void k_hist(const int* __restrict__ dst, int* __restrict__ deg, int E) {
    int i = blockIdx.x * blockDim.x + threadIdx.x;
    if (i < E) atomicAdd(&deg[dst[i]], 1);
}

// block-level exclusive scan over 1024 elements; writes per-block totals
__global__ __launch_bounds__(1024) void k_scan1(const int* __restrict__ deg, int* __restrict__ off,
                                                int* __restrict__ bsums, int N) {
    int t = threadIdx.x, b = blockIdx.x;
    int idx = b * 1024 + t;
    int v = (idx < N) ? deg[idx] : 0;
    int lane = t & 63, wid = t >> 6;
    int incl = v;
    #pragma unroll
    for (int d = 1; d < 64; d <<= 1) {
        int u = __shfl_up(incl, d);
        if (lane >= d) incl += u;
    }
    __shared__ int ws[16];
    if (lane == 63) ws[wid] = incl;
    __syncthreads();
    if (wid == 0) {
        int wv = (lane < 16) ? ws[lane] : 0;
        #pragma unroll
        for (int d = 1; d < 16; d <<= 1) {
            int u = __shfl_up(wv, d);
            if (lane >= d) wv += u;
        }
        if (lane < 16) ws[lane] = wv;  // inclusive wave sums
    }
    __syncthreads();
    int woff = (wid > 0) ? ws[wid - 1] : 0;
    if (idx < N) off[idx] = woff + incl - v;  // exclusive within block
    if (t == 0) bsums[b] = ws[15];            // block total
}

// single-block exclusive scan of up to 1024 block sums
__global__ __launch_bounds__(1024) void k_scan2(int* __restrict__ bs, int nb) {
    __shared__ int s[1024];
    int t = threadIdx.x;
    s[t] = (t < nb) ? bs[t] : 0;
    __syncthreads();
    for (int d = 1; d < 1024; d <<= 1) {
        int v = (t >= d) ? s[t - d] : 0;
        __syncthreads();
        s[t] += v;
        __syncthreads();
    }
    if (t < nb) bs[t] = t ? s[t - 1] : 0;
}

__global__ __launch_bounds__(1024) void k_scan3(int* __restrict__ off, const int* __restrict__ bs, int N) {
    int i = blockIdx.x * 1024 + threadIdx.x;
    if (i < N) off[i] += bs[blockIdx.x];
}

__global__ void k_scatter(const int* __restrict__ src, const int* __restrict__ dst,
                          const int* __restrict__ off, int* __restrict__ cur,
                          int* __restrict__ csr, int E) {
    int i = blockIdx.x * blockDim.x + threadIdx.x;
    if (i < E) {
        int d = dst[i];
        int pos = off[d] + atomicAdd(&cur[d], 1);
        csr[pos] = src[i];
    }
}

// ---------------- GEMM: XW = X[N,K] @ W[K,64], fused attention logits ----------------
// Block = 64 rows, wave = 16 rows, lane = output column.
// X staged per 64-k chunk via global_load_lds (16B width), double-buffered.
// Compute reads X as same-address broadcast ds_read_b128 (conflict-free).
// W loaded from global in 8-wide chunks (lane=col -> coalesced, L1-resident).
// REGISTER-PRESSURE HISTORY (do not regress):
//   r3: __launch_bounds__(256,4) clamped VGPR=64 -> Wreg spilled -> 2.4 GB scratch.
//   r4: K=64 variant is straight-line code (NKC=1) -> pre-RA scheduler clustered
//       all 64 ds_read_b128 + 64 W loads -> VGPR=256, acc spilled, 1.45 GB scratch.
//       (K=256 variant escaped only because its dynamic kc loop bounds the scope.)
//   r5: sched_barrier(0) per row-quad: NO effect (VGPR still 256) — the builtin
//       does not constrain the pass doing this clustering.
//   r6: bound the scope STRUCTURALLY: dynamic jh loop (unroll-disable), body =
//       8 W loads + 32 ds_read + 128 FMA -> ~70 live VGPR even fully clustered.
template <int K>
__global__ __launch_bounds__(256) void k_gemm(const float* __restrict__ X, const float* __restrict__ W,
                                              const float* __restrict__ a_s, const float* __restrict__ a_d,
                                              float* __restrict__ XW, float* __restrict__ Ssrc,
                                              float* __restrict__ Sdst, int N) {
    constexpr int NKC = K / 64;
    constexpr int NBUF = (NKC > 1) ? 2 : 1;
    __shared__ __align__(16) float Xs[NBUF][64 * 64];
    int t = threadIdx.x, lane = t & 63, wid = t >> 6;
    int rbase = blockIdx.x * 64;

    auto stage = [&](int b, int kc) {
        int kbase = kc * 64;
        #pragma unroll
        for (int i = 0; i < 4; i++) {
            int seg = wid * 4 + i;                       // wave-uniform
            int row = rbase + seg * 4 + (lane >> 4);     // 4 rows per instr
            row = row < N ? row : N - 1;
            const float* g = X + (size_t)row * K + kbase + (lane & 15) * 4;
            __builtin_amdgcn_global_load_lds(
                (const __attribute__((address_space(1))) unsigned int*)g,
                (__attribute__((address_space(3))) unsigned int*)&Xs[b][seg * 256],
                16, 0, 0);
        }
    };

    float as = a_s[lane], ad = a_d[lane];
    float acc[16];
    #pragma unroll
    for (int r = 0; r < 16; r++) acc[r] = 0.f;

    stage(0, 0);
    __syncthreads();

    for (int kc = 0; kc < NKC; kc++) {
        if (kc + 1 < NKC) stage((kc + 1) & 1, kc + 1);  // prefetch: in flight during compute

        const float* wp = W + (size_t)kc * 64 * 64 + lane;
        const float* xb = &Xs[kc & (NBUF - 1)][wid * 16 * 64];

        // dynamic loop (unroll disabled) = hard scheduling-scope boundary;
        // the body's worst-case clustering fits in registers (see history above)
        #pragma clang loop unroll(disable)
        for (int jh = 0; jh < 64; jh += 8) {
            float Wreg[8];
            #pragma unroll
            for (int j = 0; j < 8; j++) Wreg[j] = wp[(size_t)(jh + j) * 64];
            #pragma unroll
            for (int q = 0; q < 4; q++) {
                #pragma unroll
                for (int j4 = 0; j4 < 2; j4++) {
                    float4 x0 = *(const float4*)&xb[(q * 4 + 0) * 64 + jh + j4 * 4];
                    float4 x1 = *(const float4*)&xb[(q * 4 + 1) * 64 + jh + j4 * 4];
                    float4 x2 = *(const float4*)&xb[(q * 4 + 2) * 64 + jh + j4 * 4];
                    float4 x3 = *(const float4*)&xb[(q * 4 + 3) * 64 + jh + j4 * 4];
                    float w0 = Wreg[j4 * 4], w1 = Wreg[j4 * 4 + 1];
                    float w2 = Wreg[j4 * 4 + 2], w3 = Wreg[j4 * 4 + 3];
                    acc[q * 4 + 0] += x0.x * w0; acc[q * 4 + 1] += x1.x * w0;
                    acc[q * 4 + 2] += x2.x * w0; acc[q * 4 + 3] += x3.x * w0;
                    acc[q * 4 + 0] += x0.y * w1; acc[q * 4 + 1] += x1.y * w1;
                    acc[q * 4 + 2] += x2.y * w1; acc[q * 4 + 3] += x3.y * w1;
                    acc[q * 4 + 0] += x0.z * w2; acc[q * 4 + 1] += x1.z * w2;
                    acc[q * 4 + 2] += x2.z * w2; acc[q * 4 + 3] += x3.z * w2;
                    acc[q * 4 + 0] += x0.w * w3; acc[q * 4 + 1] += x1.w * w3;
                    acc[q * 4 + 2] += x2.w * w3; acc[q * 4 + 3] += x3.w * w3;
                }
            }
        }
        __syncthreads();  // drains prefetch (issued ~2500 cyc ago) + protects buffer reuse
    }

    // epilogue: write XW rows + attention logit reductions
    #pragma unroll
    for (int r = 0; r < 16; r++) {
        int row = rbase + wid * 16 + r;
        if (row < N) {
            XW[(size_t)row * 64 + lane] = acc[r];
            float vs = acc[r] * as, vd = acc[r] * ad;
            #pragma unroll
            for (int d = 32; d > 0; d >>= 1) {
                vs += __shfl_xor(vs, d);
                vd += __shfl_xor(vd, d);
            }
            if (lane == 0) { Ssrc[row] = vs; Sdst[row] = vd; }
        }
    }
}

// ---------------- attention + aggregate: one wave per dst node ----------------
__global__ __launch_bounds__(256) void k_attn(const float* __restrict__ XW, const float* __restrict__ Ssrc,
                                              const float* __restrict__ Sdst, const int* __restrict__ csr,
                                              const int* __restrict__ off, const int* __restrict__ deg,
                                              const float* __restrict__ bias, float* __restrict__ H,
                                              int N, int do_relu) {
    int t = threadIdx.x, lane = t & 63, wid = t >> 6;
    int n = blockIdx.x * 4 + wid;
    if (n >= N) return;
    float sd = Sdst[n];
    int st = off[n], d = deg[n];

    // phase 1: max over edges (lanes parallel over edges); cache first 64 src/e in regs
    float eself = lrelu(Ssrc[n] + sd);
    float m = eself;
    int myS = 0;
    float myE = -1e30f;
    if (lane < d) {
        myS = csr[st + lane];
        myE = lrelu(Ssrc[myS] + sd);
        m = fmaxf(m, myE);
    }
    for (int i = 64 + lane; i < d; i += 64) {
        int s = csr[st + i];
        m = fmaxf(m, lrelu(Ssrc[s] + sd));
    }
    #pragma unroll
    for (int dd = 32; dd > 0; dd >>= 1) m = fmaxf(m, __shfl_xor(m, dd));

    // phase 2: serial over edges, lanes = feature dims
    float w0 = __expf(eself - m);
    float denom = w0;
    float acc = w0 * XW[(size_t)n * 64 + lane];
    int dcap = d < 64 ? d : 64;
    for (int i = 0; i < dcap; i++) {
        int s = __shfl(myS, i);
        float e = __shfl(myE, i);
        float w = __expf(e - m);
        denom += w;
        acc += w * XW[(size_t)s * 64 + lane];
    }
    for (int i = 64; i < d; i++) {
        int s = csr[st + i];
        float e = lrelu(Ssrc[s] + sd);
        float w = __expf(e - m);
        denom += w;
        acc += w * XW[(size_t)s * 64 + lane];
    }
    float o = acc / denom + bias[lane];
    if (do_relu) o = fmaxf(o, 0.f);
    H[(size_t)n * 64 + lane] = o;
}

// ---------------- head: out[i] = [h[u]; h[m]] . fcW + fcb ----------------
__global__ __launch_bounds__(256) void k_head(const float* __restrict__ H, const int* __restrict__ ui,
                                              const int* __restrict__ mi, const float* __restrict__ fcW,
                                              const float* __restrict__ fcb, float* __restrict__ out, int B) {
    int t = threadIdx.x, lane = t & 63, wid = t >> 6;
    int i = blockIdx.x * 4 + wid;
    if (i >= B) return;
    int u = ui[i], m = mi[i];
    float v = H[(size_t)u * 64 + lane] * fcW[lane] + H[(size_t)m * 64 + lane] * fcW[64 + lane];
    #pragma unroll
    for (int dd = 32; dd > 0; dd >>= 1) v += __shfl_xor(v, dd);
    if (lane == 0) out[i] = v + fcb[0];
}

extern "C" void kernel_launch(void* const* d_in, const int* in_sizes, int n_in,
                              void* d_out, int out_size, void* d_ws, size_t ws_size,
                              hipStream_t stream) {
    const float* x   = (const float*)d_in[0];
    const int*   ei  = (const int*)d_in[1];
    const int*   ui  = (const int*)d_in[2];
    const int*   mi  = (const int*)d_in[3];
    const float* W1  = (const float*)d_in[4];
    const float* as1 = (const float*)d_in[5];
    const float* ad1 = (const float*)d_in[6];
    const float* b1  = (const float*)d_in[7];
    const float* W2  = (const float*)d_in[8];
    const float* as2 = (const float*)d_in[9];
    const float* ad2 = (const float*)d_in[10];
    const float* b2  = (const float*)d_in[11];
    const float* fcW = (const float*)d_in[12];
    const float* fcb = (const float*)d_in[13];
    float* out = (float*)d_out;

    const int Hdim = in_sizes[5];            // 64
    const int FIN  = in_sizes[4] / Hdim;     // 256
    const int N    = in_sizes[0] / FIN;      // 100000
    const int E    = in_sizes[1] / 2;        // 1000000
    const int B    = in_sizes[2];            // 16384

    // workspace carve
    char* w = (char*)d_ws;
    auto alloc = [&](size_t bytes) -> void* {
        void* p = (void*)w;
        w += (bytes + 255) & ~(size_t)255;
        return p;
    };
    float* xw   = (float*)alloc((size_t)N * 64 * 4);
    float* hbuf = (float*)alloc((size_t)N * 64 * 4);
    float* ssrc = (float*)alloc((size_t)N * 4);
    float* sdst = (float*)alloc((size_t)N * 4);
    int* degcur = (int*)alloc((size_t)2 * N * 4);  // deg | cur contiguous
    int* deg = degcur;
    int* cur = degcur + N;
    int* offv  = (int*)alloc((size_t)N * 4);
    int* bsums = (int*)alloc((size_t)1024 * 4);
    int* csr   = (int*)alloc((size_t)E * 4);

    const int* esrc = ei;
    const int* edst = ei + E;

    // --- build CSR by dst (shared by both layers) ---
    k_zero<<<(2 * N + 1023) / 1024, 1024, 0, stream>>>(degcur, 2 * N);
    k_hist<<<(E + 255) / 256, 256, 0, stream>>>(edst, deg, E);
    int nb = (N + 1023) / 1024;
    k_scan1<<<nb, 1024, 0, stream>>>(deg, offv, bsums, N);
    k_scan2<<<1, 1024, 0, stream>>>(bsums, nb);
    k_scan3<<<nb, 1024, 0, stream>>>(offv, bsums, N);
    k_scatter<<<(E + 255) / 256, 256, 0, stream>>>(esrc, edst, offv, cur, csr, E);

    const int gemmBlocks = (N + 63) / 64;

    // --- layer 1 ---
    k_gemm<256><<<gemmBlocks, 256, 0, stream>>>(x, W1, as1, ad1, xw, ssrc, sdst, N);
    k_attn<<<(N + 3) / 4, 256, 0, stream>>>(xw, ssrc, sdst, csr, offv, deg, b1, hbuf, N, 1);

    // --- layer 2 (xw buffer reused) ---
    k_gemm<64><<<gemmBlocks, 256, 0, stream>>>(hbuf, W2, as2, ad2, xw, ssrc, sdst, N);
    k_attn<<<(N + 3) / 4, 256, 0, stream>>>(xw, ssrc, sdst, csr, offv, deg, b2, hbuf, N, 0);

    // --- head ---
    k_head<<<(B + 3) / 4, 256, 0, stream>>>(hbuf, ui, mi, fcW, fcb, out, B);
}